// Round 1
// baseline (128.347 us; speedup 1.0000x reference)
//
#include <hip/hip_runtime.h>
#include <math.h>

#define TPB   256
#define PER   16
#define CHUNK 4096      // TPB * PER
#define NCH   256       // TLEN / CHUNK
#define TLEN  1048576
#define K1OFF 15        // 65047 / 4096
#define LOFF  3607      // 65047 % 4096
#define NEMA  4         // 0: short/pred, 1: short/targ, 2: long/pred, 3: long/targ

// Inclusive Hillis-Steele scan over TPB (a,b) pairs in thread order with
// combine(l, r) = (l.a*r.a, r.a*l.b + r.b). Returns exclusive prefix in
// (ea, eb); optionally the block total in (*ta, *tb).
__device__ __forceinline__ void block_scan_excl(float a, float b,
    float* sa, float* sb, float& ea, float& eb, float* ta, float* tb)
{
    const int j = threadIdx.x;
    float ca = a, cb = b;
    sa[j] = ca; sb[j] = cb;
    __syncthreads();
    #pragma unroll
    for (int d = 1; d < TPB; d <<= 1) {
        float pa = 1.0f, pb = 0.0f;
        if (j >= d) { pa = sa[j - d]; pb = sb[j - d]; }
        __syncthreads();
        cb = fmaf(ca, pb, cb);   // r.a * l.b + r.b   (old ca is r.a)
        ca = ca * pa;
        sa[j] = ca; sb[j] = cb;
        __syncthreads();
    }
    ea = (j == 0) ? 1.0f : sa[j - 1];
    eb = (j == 0) ? 0.0f : sb[j - 1];
    if (ta) { *ta = sa[TPB - 1]; *tb = sb[TPB - 1]; }
    __syncthreads();   // safe reuse of sa/sb by caller
}

// Full EMA over one CHUNK: given carry-in y_in (y value just before the
// chunk), produce this thread's PER y-values.
__device__ __forceinline__ void ema_chunk(const float* __restrict__ x,
    float am, float c, float y_in, float* sa, float* sb, float yv[PER])
{
    const int j = threadIdx.x;
    float xv[PER];
    const float4* x4 = (const float4*)(x + (size_t)j * PER);
    #pragma unroll
    for (int q = 0; q < PER / 4; ++q) {
        float4 v = x4[q];
        xv[q*4+0] = v.x; xv[q*4+1] = v.y; xv[q*4+2] = v.z; xv[q*4+3] = v.w;
    }
    float a = 1.0f, b = 0.0f;
    #pragma unroll
    for (int e = 0; e < PER; ++e) { b = fmaf(am, b, c * xv[e]); a *= am; }
    float ea, eb;
    block_scan_excl(a, b, sa, sb, ea, eb, nullptr, nullptr);
    float y = fmaf(ea, y_in, eb);   // y right before this thread's first elem
    #pragma unroll
    for (int e = 0; e < PER; ++e) { y = fmaf(am, y, c * xv[e]); yv[e] = y; }
}

// Pass 1: per-chunk (A,B) aggregates for the 4 EMAs.
__global__ __launch_bounds__(TPB) void ldr_partials(
    const float* __restrict__ pred, const float* __restrict__ targ,
    float aS, float cS, float aL, float cL,
    float* __restrict__ pA, float* __restrict__ pB, int rows)
{
    __shared__ float sa[TPB], sb[TPB];
    const int k = blockIdx.x, r = blockIdx.y, j = threadIdx.x;
    const size_t base = (size_t)r * TLEN + (size_t)k * CHUNK + (size_t)j * PER;
    float xp[PER], xt[PER];
    {
        const float4* p4 = (const float4*)(pred + base);
        const float4* t4 = (const float4*)(targ + base);
        #pragma unroll
        for (int q = 0; q < PER / 4; ++q) {
            float4 v = p4[q];
            xp[q*4+0] = v.x; xp[q*4+1] = v.y; xp[q*4+2] = v.z; xp[q*4+3] = v.w;
            float4 w = t4[q];
            xt[q*4+0] = w.x; xt[q*4+1] = w.y; xt[q*4+2] = w.z; xt[q*4+3] = w.w;
        }
    }
    float ta, tb;
    #define DO_AGG(E, XV, AM, CC) {                                           \
        float a = 1.0f, b = 0.0f;                                             \
        _Pragma("unroll")                                                     \
        for (int e = 0; e < PER; ++e) { b = fmaf(AM, b, CC * XV[e]); a *= AM; } \
        float ea_, eb_;                                                       \
        block_scan_excl(a, b, sa, sb, ea_, eb_, &ta, &tb);                    \
        if (j == 0) {                                                         \
            size_t idx = ((size_t)(E) * rows + r) * NCH + k;                  \
            pA[idx] = ta; pB[idx] = tb;                                       \
        } }
    DO_AGG(0, xp, aS, cS)
    DO_AGG(1, xt, aS, cS)
    DO_AGG(2, xp, aL, cL)
    DO_AGG(3, xt, aL, cL)
    #undef DO_AGG
}

// Pass 2: per (ema,row), scan the NCH chunk aggregates -> carry-in per chunk.
// One wave per block; lane handles 4 consecutive chunks.
__global__ __launch_bounds__(64) void ldr_carry(
    const float* __restrict__ pA, const float* __restrict__ pB,
    float* __restrict__ cin)
{
    const int g = blockIdx.x;       // e*rows + r
    const int lane = threadIdx.x;   // 0..63
    const float* A  = pA + (size_t)g * NCH;
    const float* Bv = pB + (size_t)g * NCH;
    float a4[4], b4[4];
    float a = 1.0f, b = 0.0f;
    #pragma unroll
    for (int m = 0; m < 4; ++m) {
        a4[m] = A[lane * 4 + m]; b4[m] = Bv[lane * 4 + m];
        b = fmaf(a4[m], b, b4[m]);  // combine(acc, chunk)
        a *= a4[m];
    }
    #pragma unroll
    for (int d = 1; d < 64; d <<= 1) {
        float pa = __shfl_up(a, d, 64);
        float pb = __shfl_up(b, d, 64);
        if (lane >= d) { b = fmaf(a, pb, b); a *= pa; }
    }
    float eb = __shfl_up(b, 1, 64);
    float carry = (lane == 0) ? 0.0f : eb;   // y at end of previous chunks
    float* co = cin + (size_t)g * NCH;
    #pragma unroll
    for (int m = 0; m < 4; ++m) {
        co[lane * 4 + m] = carry;
        carry = fmaf(a4[m], carry, b4[m]);
    }
}

// Pass 3: fused loss. Block (k, r): u over chunk k (short EMAs), shifted v
// window from long EMAs of chunks k+15 (tail from local offset LOFF) and
// k+16 (head below LOFF), assembled in LDS W[0..CHUNK).
__global__ __launch_bounds__(TPB) void ldr_loss(
    const float* __restrict__ pred, const float* __restrict__ targ,
    const float* __restrict__ cin,
    float aS, float cS, float aL, float cL,
    double* __restrict__ acc, int rows)
{
    __shared__ float W[CHUNK];
    __shared__ float sa[TPB], sb[TPB];
    const int k = blockIdx.x, r = blockIdx.y, j = threadIdx.x;
    const int k1 = (k + K1OFF) % NCH;
    const int k2 = (k + K1OFF + 1) % NCH;
    const size_t rb = (size_t)r * TLEN;
    float yv[PER], yp[PER];
    #define CIN(E, KC) cin[((size_t)(E) * rows + r) * NCH + (KC)]

    // v window part 1: chunk k1, local offsets [LOFF, CHUNK) -> W[0..489)
    ema_chunk(pred + rb + (size_t)k1 * CHUNK, aL, cL, CIN(2, k1), sa, sb, yv);
    #pragma unroll
    for (int e = 0; e < PER; ++e) {
        int l = j * PER + e;
        if (l >= LOFF) W[l - LOFF] = yv[e];
    }
    ema_chunk(targ + rb + (size_t)k1 * CHUNK, aL, cL, CIN(3, k1), sa, sb, yv);
    #pragma unroll
    for (int e = 0; e < PER; ++e) {
        int l = j * PER + e;
        if (l >= LOFF) W[l - LOFF] = __logf(__fdividef(W[l - LOFF], yv[e]));
    }
    // v window part 2: chunk k2, local offsets [0, LOFF) -> W[489..CHUNK)
    ema_chunk(pred + rb + (size_t)k2 * CHUNK, aL, cL, CIN(2, k2), sa, sb, yv);
    #pragma unroll
    for (int e = 0; e < PER; ++e) {
        int l = j * PER + e;
        if (l < LOFF) W[l + (CHUNK - LOFF)] = yv[e];
    }
    ema_chunk(targ + rb + (size_t)k2 * CHUNK, aL, cL, CIN(3, k2), sa, sb, yv);
    #pragma unroll
    for (int e = 0; e < PER; ++e) {
        int l = j * PER + e;
        if (l < LOFF) {
            float w = W[l + (CHUNK - LOFF)];
            W[l + (CHUNK - LOFF)] = __logf(__fdividef(w, yv[e]));
        }
    }
    // u over chunk k (short EMAs)
    ema_chunk(pred + rb + (size_t)k * CHUNK, aS, cS, CIN(0, k), sa, sb, yp);
    ema_chunk(targ + rb + (size_t)k * CHUNK, aS, cS, CIN(1, k), sa, sb, yv);

    float lsum = 0.0f;
    #pragma unroll
    for (int e = 0; e < PER; ++e) {
        int l = j * PER + e;
        float u = __logf(__fdividef(yp[e], yv[e]));
        lsum += fabsf(u - W[l]);
    }
    #undef CIN

    sa[j] = lsum;
    __syncthreads();
    #pragma unroll
    for (int d = TPB / 2; d > 0; d >>= 1) {
        if (j < d) sa[j] += sa[j + d];
        __syncthreads();
    }
    if (j == 0) atomicAdd(acc, (double)sa[0]);
}

__global__ void ldr_finalize(const double* __restrict__ acc,
                             float* __restrict__ out, double inv_n)
{
    out[0] = (float)(acc[0] * inv_n);
}

extern "C" void kernel_launch(void* const* d_in, const int* in_sizes, int n_in,
                              void* d_out, int out_size, void* d_ws, size_t ws_size,
                              hipStream_t stream)
{
    const float* pred = (const float*)d_in[0];
    const float* targ = (const float*)d_in[1];
    const int n = in_sizes[0];
    const int rows = n / TLEN;   // 16

    // Coefs exactly as the reference: double math, cast to f32 at use.
    const double csd = 1.0 - exp(-2200.0 / (50.0 * 44100.0));
    const double cld = 1.0 - exp(-2200.0 / (3000.0 * 44100.0));
    const float cS = (float)csd, cL = (float)cld;
    const float aS = (float)(1.0 - csd), aL = (float)(1.0 - cld);

    // ws layout: [0,8): double acc; then pA, pB, cin (NEMA*rows*NCH floats each)
    char* wsb = (char*)d_ws;
    double* acc = (double*)wsb;
    float* pA  = (float*)(wsb + 256);
    float* pB  = pA + (size_t)NEMA * rows * NCH;
    float* cin = pB + (size_t)NEMA * rows * NCH;

    hipMemsetAsync(acc, 0, sizeof(double), stream);

    dim3 grid(NCH, rows);
    ldr_partials<<<grid, TPB, 0, stream>>>(pred, targ, aS, cS, aL, cL, pA, pB, rows);
    ldr_carry<<<NEMA * rows, 64, 0, stream>>>(pA, pB, cin);
    ldr_loss<<<grid, TPB, 0, stream>>>(pred, targ, cin, aS, cS, aL, cL, acc, rows);

    const double inv_n = 1.0 / ((double)rows * (double)TLEN);
    ldr_finalize<<<1, 1, 0, stream>>>(acc, (float*)d_out, inv_n);
}

// Round 3
// 115.024 us; speedup vs baseline: 1.1158x; 1.1158x over previous
//
#include <hip/hip_runtime.h>
#include <math.h>

#define TPB   256
#define PER   16
#define CHUNK 4096      // TPB * PER
#define NCH   256       // TLEN / CHUNK
#define TLEN  1048576
#define K1OFF 15        // 65047 / 4096
#define LOFF  3607      // 65047 % 4096
#define NEMA  4         // 0: short/pred, 1: short/targ, 2: long/pred, 3: long/targ

// integer power by repeated squaring (<=8 iters), deterministic
__device__ __forceinline__ float ipowf(float base, int e) {
    float r = 1.0f, p = base;
    while (e) { if (e & 1) r *= p; p *= p; e >>= 1; }
    return r;
}

// Transposed LDS layout for the aligned v-window: conflict-free for both the
// shifted writes and the aligned reads (lanes land on consecutive addresses).
__device__ __forceinline__ int waddr(int t) { return (t & 15) * 256 + (t >> 4); }

// EMA over one CHUNK using the constant-multiplier structure:
// every thread's segment coefficient is the SAME constant A16 = am^16, so the
// cross-thread prefix is a register-only wave scan of b with constant
// multipliers + one 4-float LDS hop across the 4 waves (single barrier).
// A wave covers 64*16 = 1024 elements -> cross-wave coefficient A1024.
__device__ __forceinline__ void ema_chunk2(
    const float* __restrict__ x, float am, float c, float A16, float A1024,
    float aLane /*A16^lane*/, float aThread /*am^(16*j)*/, float y_cin,
    float* slot /*4 floats, unique per call*/, float yv[PER])
{
    const int j = threadIdx.x, lane = j & 63, w = j >> 6;
    float xv[PER];
    const float4* x4 = (const float4*)(x + (size_t)j * PER);
    #pragma unroll
    for (int q = 0; q < PER / 4; ++q) {
        float4 v = x4[q];
        xv[q*4+0] = v.x; xv[q*4+1] = v.y; xv[q*4+2] = v.z; xv[q*4+3] = v.w;
    }
    // per-thread segment partial: b = sum_e c*x[e]*am^(15-e)
    float b = 0.0f;
    #pragma unroll
    for (int e = 0; e < PER; ++e) b = fmaf(am, b, c * xv[e]);
    // wave inclusive scan with constant multiplier A16
    float incl = b, Ad = A16;
    #pragma unroll
    for (int d = 1; d < 64; d <<= 1) {
        float pb = __shfl_up(incl, d, 64);
        if (lane >= d) incl = fmaf(Ad, pb, incl);
        Ad *= Ad;
    }
    float excl = __shfl_up(incl, 1, 64);
    if (lane == 0) excl = 0.0f;
    if (lane == 63) slot[w] = incl;          // wave total (1024 elements)
    __syncthreads();
    // carry across waves: Wc = sum_{w'<w} T_w' * A1024^(w-1-w')
    float Wc = 0.0f;
    for (int u = 0; u < w; ++u) Wc = fmaf(Wc, A1024, slot[u]);
    // y just before this thread's first element
    float y = fmaf(aThread, y_cin, fmaf(aLane, Wc, excl));
    #pragma unroll
    for (int e = 0; e < PER; ++e) { y = fmaf(am, y, c * xv[e]); yv[e] = y; }
}

// Pass 1: per-chunk EMA aggregates. No scan needed: total = sum_j b_j * A16^(255-j).
__global__ __launch_bounds__(TPB) void ldr_partials(
    const float* __restrict__ pred, const float* __restrict__ targ,
    float aS, float cS, float aL, float cL, float A16S, float A16L,
    float* __restrict__ pB, int rows)
{
    __shared__ float red[4][NEMA];
    const int k = blockIdx.x, r = blockIdx.y, j = threadIdx.x;
    const int lane = j & 63, w = j >> 6;
    const size_t base = (size_t)r * TLEN + (size_t)k * CHUNK + (size_t)j * PER;
    float xp[PER], xt[PER];
    {
        const float4* p4 = (const float4*)(pred + base);
        const float4* t4 = (const float4*)(targ + base);
        #pragma unroll
        for (int q = 0; q < PER / 4; ++q) {
            float4 v = p4[q];
            xp[q*4+0] = v.x; xp[q*4+1] = v.y; xp[q*4+2] = v.z; xp[q*4+3] = v.w;
            float4 u = t4[q];
            xt[q*4+0] = u.x; xt[q*4+1] = u.y; xt[q*4+2] = u.z; xt[q*4+3] = u.w;
        }
    }
    const float wgtS = ipowf(A16S, 255 - j);
    const float wgtL = ipowf(A16L, 255 - j);
    float v[NEMA];
    #define SEG(E, XV, AM, CC, WG) {                                          \
        float b = 0.0f;                                                       \
        _Pragma("unroll")                                                     \
        for (int e = 0; e < PER; ++e) b = fmaf(AM, b, CC * XV[e]);            \
        v[E] = b * WG; }
    SEG(0, xp, aS, cS, wgtS)
    SEG(1, xt, aS, cS, wgtS)
    SEG(2, xp, aL, cL, wgtL)
    SEG(3, xt, aL, cL, wgtL)
    #undef SEG
    #pragma unroll
    for (int E = 0; E < NEMA; ++E) {
        float s = v[E];
        #pragma unroll
        for (int d = 32; d > 0; d >>= 1) s += __shfl_xor(s, d, 64);
        if (lane == 0) red[w][E] = s;
    }
    __syncthreads();
    if (j == 0) {
        #pragma unroll
        for (int E = 0; E < NEMA; ++E) {
            float s = red[0][E] + red[1][E] + red[2][E] + red[3][E];
            pB[((size_t)E * rows + r) * NCH + k] = s;
        }
    }
}

// Pass 2: carry-in per chunk. Chunk coefficient is the constant am^4096;
// each lane covers 4 chunks -> lane-segment coefficient am^16384.
__global__ __launch_bounds__(64) void ldr_carry(
    const float* __restrict__ pB, float* __restrict__ cin,
    float AcS, float AcS4, float AcL, float AcL4, int rows)
{
    const int g = blockIdx.x;              // e*rows + r
    const int lane = threadIdx.x;
    const bool isShort = g < 2 * rows;
    const float Ac  = isShort ? AcS  : AcL;
    const float AcW = isShort ? AcS4 : AcL4;
    const float* Bv = pB + (size_t)g * NCH;
    float b4[4];
    float B = 0.0f;
    #pragma unroll
    for (int m = 0; m < 4; ++m) {
        b4[m] = Bv[lane * 4 + m];
        B = fmaf(Ac, B, b4[m]);
    }
    float incl = B, Ad = AcW;
    #pragma unroll
    for (int d = 1; d < 64; d <<= 1) {
        float pb = __shfl_up(incl, d, 64);
        if (lane >= d) incl = fmaf(Ad, pb, incl);
        Ad *= Ad;
    }
    float excl = __shfl_up(incl, 1, 64);
    if (lane == 0) excl = 0.0f;
    float carry = excl;
    float* co = cin + (size_t)g * NCH;
    #pragma unroll
    for (int m = 0; m < 4; ++m) {
        co[lane * 4 + m] = carry;
        carry = fmaf(Ac, carry, b4[m]);
    }
}

// Pass 3: fused loss with transposed (conflict-free) v-window in LDS.
__global__ __launch_bounds__(TPB) void ldr_loss(
    const float* __restrict__ pred, const float* __restrict__ targ,
    const float* __restrict__ cin,
    float aS, float cS, float aL, float cL,
    float A16S, float A1024S, float A16L, float A1024L,
    double* __restrict__ acc, int rows)
{
    __shared__ float W[CHUNK];
    __shared__ float slots[6][4];
    __shared__ float rsum[4];
    const int k = blockIdx.x, r = blockIdx.y, j = threadIdx.x;
    const int lane = j & 63, w = j >> 6;
    const int k1 = (k + K1OFF) % NCH;
    const int k2 = (k + K1OFF + 1) % NCH;
    const size_t rb = (size_t)r * TLEN;
    const float pSl = ipowf(A16S, lane), pLl = ipowf(A16L, lane);
    const float aTS = pSl * ipowf(A1024S, w), aTL = pLl * ipowf(A1024L, w);
    float yv[PER], yp[PER];
    #define CIN(E, KC) cin[((size_t)(E) * rows + r) * NCH + (KC)]

    // v window part 1: chunk k1, elements with local l >= LOFF -> t = l-LOFF
    ema_chunk2(pred + rb + (size_t)k1 * CHUNK, aL, cL, A16L, A1024L, pLl, aTL,
               CIN(2, k1), slots[0], yv);
    #pragma unroll
    for (int e = 0; e < PER; ++e) {
        int t = j * PER + e - LOFF;
        if (t >= 0) W[waddr(t)] = yv[e];
    }
    ema_chunk2(targ + rb + (size_t)k1 * CHUNK, aL, cL, A16L, A1024L, pLl, aTL,
               CIN(3, k1), slots[1], yv);
    #pragma unroll
    for (int e = 0; e < PER; ++e) {
        int t = j * PER + e - LOFF;
        if (t >= 0) { int a = waddr(t); W[a] = __logf(__fdividef(W[a], yv[e])); }
    }
    // v window part 2: chunk k2, elements with local l < LOFF -> t = l + (CHUNK-LOFF)
    ema_chunk2(pred + rb + (size_t)k2 * CHUNK, aL, cL, A16L, A1024L, pLl, aTL,
               CIN(2, k2), slots[2], yv);
    #pragma unroll
    for (int e = 0; e < PER; ++e) {
        int l = j * PER + e;
        if (l < LOFF) W[waddr(l + (CHUNK - LOFF))] = yv[e];
    }
    ema_chunk2(targ + rb + (size_t)k2 * CHUNK, aL, cL, A16L, A1024L, pLl, aTL,
               CIN(3, k2), slots[3], yv);
    #pragma unroll
    for (int e = 0; e < PER; ++e) {
        int l = j * PER + e;
        if (l < LOFF) {
            int a = waddr(l + (CHUNK - LOFF));
            W[a] = __logf(__fdividef(W[a], yv[e]));
        }
    }
    // u over chunk k (short EMAs); each call's internal barrier also orders
    // the W writes above against the cross-thread reads below.
    ema_chunk2(pred + rb + (size_t)k * CHUNK, aS, cS, A16S, A1024S, pSl, aTS,
               CIN(0, k), slots[4], yp);
    ema_chunk2(targ + rb + (size_t)k * CHUNK, aS, cS, A16S, A1024S, pSl, aTS,
               CIN(1, k), slots[5], yv);

    float lsum = 0.0f;
    #pragma unroll
    for (int e = 0; e < PER; ++e) {
        int l = j * PER + e;
        float u = __logf(__fdividef(yp[e], yv[e]));
        lsum += fabsf(u - W[waddr(l)]);    // read addr = e*256 + j, conflict-free
    }
    #undef CIN

    #pragma unroll
    for (int d = 32; d > 0; d >>= 1) lsum += __shfl_xor(lsum, d, 64);
    if (lane == 0) rsum[w] = lsum;
    __syncthreads();
    if (j == 0) atomicAdd(acc, (double)(rsum[0] + rsum[1] + rsum[2] + rsum[3]));
}

__global__ void ldr_finalize(const double* __restrict__ acc,
                             float* __restrict__ out, double inv_n)
{
    out[0] = (float)(acc[0] * inv_n);
}

extern "C" void kernel_launch(void* const* d_in, const int* in_sizes, int n_in,
                              void* d_out, int out_size, void* d_ws, size_t ws_size,
                              hipStream_t stream)
{
    const float* pred = (const float*)d_in[0];
    const float* targ = (const float*)d_in[1];
    const int n = in_sizes[0];
    const int rows = n / TLEN;   // 16

    const double csd = 1.0 - exp(-2200.0 / (50.0 * 44100.0));
    const double cld = 1.0 - exp(-2200.0 / (3000.0 * 44100.0));
    const float cS = (float)csd, cL = (float)cld;
    const float aS = (float)(1.0 - csd), aL = (float)(1.0 - cld);
    const float A16S   = (float)pow(1.0 - csd, 16.0);
    const float A1024S = (float)pow(1.0 - csd, 1024.0);
    const float A16L   = (float)pow(1.0 - cld, 16.0);
    const float A1024L = (float)pow(1.0 - cld, 1024.0);
    const float AcS  = (float)pow(1.0 - csd, 4096.0);
    const float AcS4 = (float)pow(1.0 - csd, 16384.0);
    const float AcL  = (float)pow(1.0 - cld, 4096.0);
    const float AcL4 = (float)pow(1.0 - cld, 16384.0);

    // ws layout: [0,8): double acc; then pB, cin (NEMA*rows*NCH floats each)
    char* wsb = (char*)d_ws;
    double* acc = (double*)wsb;
    float* pB  = (float*)(wsb + 256);
    float* cin = pB + (size_t)NEMA * rows * NCH;

    hipMemsetAsync(acc, 0, sizeof(double), stream);

    dim3 grid(NCH, rows);
    ldr_partials<<<grid, TPB, 0, stream>>>(pred, targ, aS, cS, aL, cL,
                                           A16S, A16L, pB, rows);
    ldr_carry<<<NEMA * rows, 64, 0, stream>>>(pB, cin, AcS, AcS4, AcL, AcL4, rows);
    ldr_loss<<<grid, TPB, 0, stream>>>(pred, targ, cin, aS, cS, aL, cL,
                                       A16S, A1024S, A16L, A1024L, acc, rows);

    const double inv_n = 1.0 / ((double)rows * (double)TLEN);
    ldr_finalize<<<1, 1, 0, stream>>>(acc, (float*)d_out, inv_n);
}

// Round 4
// 101.072 us; speedup vs baseline: 1.2698x; 1.1380x over previous
//
#include <hip/hip_runtime.h>
#include <math.h>

#define TPB   256
#define PER   16
#define CHUNK 4096      // TPB * PER
#define NCH   256       // TLEN / CHUNK
#define TLEN  1048576
#define K1OFF 15        // 65047 / 4096
#define LOFF  3607      // 65047 % 4096
#define NEMA  4         // 0: short/pred, 1: short/targ, 2: long/pred, 3: long/targ

// integer power by repeated squaring (<=8 iters), deterministic
__device__ __forceinline__ float ipowf(float base, int e) {
    float r = 1.0f, p = base;
    while (e) { if (e & 1) r *= p; p *= p; e >>= 1; }
    return r;
}

// Transposed LDS layout for the aligned v-window: conflict-free for both the
// shifted writes and the aligned reads (lanes land on consecutive addresses).
__device__ __forceinline__ int waddr(int t) { return (t & 15) * 256 + (t >> 4); }

__device__ __forceinline__ void load16(const float* __restrict__ p, float v[PER]) {
    const float4* p4 = (const float4*)(p + (size_t)threadIdx.x * PER);
    #pragma unroll
    for (int q = 0; q < PER / 4; ++q) {
        float4 t = p4[q];
        v[q*4+0] = t.x; v[q*4+1] = t.y; v[q*4+2] = t.z; v[q*4+3] = t.w;
    }
}

// Dual (pred+targ) constant-multiplier prefix for one chunk: returns the EMA
// state just before this thread's first element, for both signals.
// UNSCALED recurrence y = am*y + x (the c factor cancels in all ratios).
__device__ __forceinline__ void pair_scan(
    const float xp[PER], const float xt[PER], float am, float A16, float A1024,
    float aLane /*A16^lane*/, float aThread /*am^(16j)*/,
    float cin_p, float cin_t, float* sp_, float* st_ /*4 floats each*/,
    float& yp0, float& yt0)
{
    const int j = threadIdx.x, lane = j & 63, w = j >> 6;
    float bp = 0.0f, bt = 0.0f;
    #pragma unroll
    for (int e = 0; e < PER; ++e) {
        bp = fmaf(am, bp, xp[e]);
        bt = fmaf(am, bt, xt[e]);
    }
    float ip = bp, it = bt, Ad = A16;
    #pragma unroll
    for (int d = 1; d < 64; d <<= 1) {
        float pp = __shfl_up(ip, d, 64);
        float pt = __shfl_up(it, d, 64);
        if (lane >= d) { ip = fmaf(Ad, pp, ip); it = fmaf(Ad, pt, it); }
        Ad *= Ad;
    }
    float ep = __shfl_up(ip, 1, 64);
    float et = __shfl_up(it, 1, 64);
    if (lane == 0) { ep = 0.0f; et = 0.0f; }
    if (lane == 63) { sp_[w] = ip; st_[w] = it; }
    __syncthreads();
    float Wp = 0.0f, Wt = 0.0f;
    for (int u = 0; u < w; ++u) {
        Wp = fmaf(Wp, A1024, sp_[u]);
        Wt = fmaf(Wt, A1024, st_[u]);
    }
    yp0 = fmaf(aThread, cin_p, fmaf(aLane, Wp, ep));
    yt0 = fmaf(aThread, cin_t, fmaf(aLane, Wt, et));
}

// Pass 1: per-chunk UNSCALED EMA aggregates: total = sum_j b_j * A16^(255-j).
__global__ __launch_bounds__(TPB) void ldr_partials(
    const float* __restrict__ pred, const float* __restrict__ targ,
    float amS, float amL, float A16S, float A16L,
    float* __restrict__ pB, int rows)
{
    __shared__ float red[4][NEMA];
    const int k = blockIdx.x, r = blockIdx.y, j = threadIdx.x;
    const int lane = j & 63, w = j >> 6;
    const size_t base = (size_t)r * TLEN + (size_t)k * CHUNK;
    float xp[PER], xt[PER];
    load16(pred + base, xp);
    load16(targ + base, xt);
    const float wgtS = ipowf(A16S, 255 - j);
    const float wgtL = ipowf(A16L, 255 - j);
    float v[NEMA];
    #define SEG(E, XV, AM, WG) {                                              \
        float b = 0.0f;                                                       \
        _Pragma("unroll")                                                     \
        for (int e = 0; e < PER; ++e) b = fmaf(AM, b, XV[e]);                 \
        v[E] = b * WG; }
    SEG(0, xp, amS, wgtS)
    SEG(1, xt, amS, wgtS)
    SEG(2, xp, amL, wgtL)
    SEG(3, xt, amL, wgtL)
    #undef SEG
    #pragma unroll
    for (int E = 0; E < NEMA; ++E) {
        float s = v[E];
        #pragma unroll
        for (int d = 32; d > 0; d >>= 1) s += __shfl_xor(s, d, 64);
        if (lane == 0) red[w][E] = s;
    }
    __syncthreads();
    if (j == 0) {
        #pragma unroll
        for (int E = 0; E < NEMA; ++E) {
            float s = red[0][E] + red[1][E] + red[2][E] + red[3][E];
            pB[((size_t)E * rows + r) * NCH + k] = s;
        }
    }
}

// Pass 2: carry-in per chunk. Chunk coefficient is the constant am^4096;
// each lane covers 4 chunks -> lane-segment coefficient am^16384.
__global__ __launch_bounds__(64) void ldr_carry(
    const float* __restrict__ pB, float* __restrict__ cin,
    float AcS, float AcS4, float AcL, float AcL4, int rows)
{
    const int g = blockIdx.x;              // e*rows + r
    const int lane = threadIdx.x;
    const bool isShort = g < 2 * rows;
    const float Ac  = isShort ? AcS  : AcL;
    const float AcW = isShort ? AcS4 : AcL4;
    const float* Bv = pB + (size_t)g * NCH;
    float b4[4];
    float B = 0.0f;
    #pragma unroll
    for (int m = 0; m < 4; ++m) {
        b4[m] = Bv[lane * 4 + m];
        B = fmaf(Ac, B, b4[m]);
    }
    float incl = B, Ad = AcW;
    #pragma unroll
    for (int d = 1; d < 64; d <<= 1) {
        float pb = __shfl_up(incl, d, 64);
        if (lane >= d) incl = fmaf(Ad, pb, incl);
        Ad *= Ad;
    }
    float excl = __shfl_up(incl, 1, 64);
    if (lane == 0) excl = 0.0f;
    float carry = excl;
    float* co = cin + (size_t)g * NCH;
    #pragma unroll
    for (int m = 0; m < 4; ++m) {
        co[lane * 4 + m] = carry;
        carry = fmaf(Ac, carry, b4[m]);
    }
}

// Pass 3: fused loss. All 6 chunk loads issued up front (one latency
// exposure); 3 fused pred+targ scan phases (3 barriers total); W stores the
// long-EMA ratio lt/lp so each element needs 1 log:
//   u - v = log(sp/st) - log(lp/lt) = log( (sp/st) * (lt/lp) ).
__global__ __launch_bounds__(TPB) void ldr_loss(
    const float* __restrict__ pred, const float* __restrict__ targ,
    const float* __restrict__ cin,
    float amS, float amL,
    float A16S, float A1024S, float A16L, float A1024L,
    double* __restrict__ acc, int rows)
{
    __shared__ float W[CHUNK];
    __shared__ float slots[6][4];
    __shared__ float rsum[4];
    const int k = blockIdx.x, r = blockIdx.y, j = threadIdx.x;
    const int lane = j & 63, w = j >> 6;
    const int k1 = (k + K1OFF) % NCH;
    const int k2 = (k + K1OFF + 1) % NCH;
    const size_t rb = (size_t)r * TLEN;

    // Issue ALL global loads before any dependent compute.
    float xp1[PER], xt1[PER], xp2[PER], xt2[PER], xps[PER], xts[PER];
    load16(pred + rb + (size_t)k1 * CHUNK, xp1);
    load16(targ + rb + (size_t)k1 * CHUNK, xt1);
    load16(pred + rb + (size_t)k2 * CHUNK, xp2);
    load16(targ + rb + (size_t)k2 * CHUNK, xt2);
    load16(pred + rb + (size_t)k * CHUNK, xps);
    load16(targ + rb + (size_t)k * CHUNK, xts);
    #define CIN(E, KC) cin[((size_t)(E) * rows + r) * NCH + (KC)]
    const float cLp1 = CIN(2, k1), cLt1 = CIN(3, k1);
    const float cLp2 = CIN(2, k2), cLt2 = CIN(3, k2);
    const float cSp  = CIN(0, k),  cSt  = CIN(1, k);
    #undef CIN

    const float pSl = ipowf(A16S, lane), pLl = ipowf(A16L, lane);
    const float aTS = pSl * ipowf(A1024S, w), aTL = pLl * ipowf(A1024L, w);
    float yp, yt;

    // Phase A: long EMAs of chunk k1 -> W[t] = lt/lp for t = l - LOFF >= 0
    pair_scan(xp1, xt1, amL, A16L, A1024L, pLl, aTL, cLp1, cLt1,
              slots[0], slots[1], yp, yt);
    #pragma unroll
    for (int e = 0; e < PER; ++e) {
        yp = fmaf(amL, yp, xp1[e]);
        yt = fmaf(amL, yt, xt1[e]);
        int t = j * PER + e - LOFF;
        if (t >= 0) W[waddr(t)] = __fdividef(yt, yp);
    }
    // Phase B: long EMAs of chunk k2 -> W[l + CHUNK-LOFF] for l < LOFF
    pair_scan(xp2, xt2, amL, A16L, A1024L, pLl, aTL, cLp2, cLt2,
              slots[2], slots[3], yp, yt);
    #pragma unroll
    for (int e = 0; e < PER; ++e) {
        yp = fmaf(amL, yp, xp2[e]);
        yt = fmaf(amL, yt, xt2[e]);
        int l = j * PER + e;
        if (l < LOFF) W[waddr(l + (CHUNK - LOFF))] = __fdividef(yt, yp);
    }
    // Phase C: short EMAs of chunk k. Its internal barrier orders all W
    // writes above against the cross-thread W reads below.
    pair_scan(xps, xts, amS, A16S, A1024S, pSl, aTS, cSp, cSt,
              slots[4], slots[5], yp, yt);
    float lsum = 0.0f;
    #pragma unroll
    for (int e = 0; e < PER; ++e) {
        yp = fmaf(amS, yp, xps[e]);
        yt = fmaf(amS, yt, xts[e]);
        float q = __fdividef(yp, yt) * W[(e << 8) + j];   // waddr(16j+e)
        lsum += fabsf(__logf(q));
    }

    #pragma unroll
    for (int d = 32; d > 0; d >>= 1) lsum += __shfl_xor(lsum, d, 64);
    if (lane == 0) rsum[w] = lsum;
    __syncthreads();
    if (j == 0) atomicAdd(acc, (double)(rsum[0] + rsum[1] + rsum[2] + rsum[3]));
}

__global__ void ldr_finalize(const double* __restrict__ acc,
                             float* __restrict__ out, double inv_n)
{
    out[0] = (float)(acc[0] * inv_n);
}

extern "C" void kernel_launch(void* const* d_in, const int* in_sizes, int n_in,
                              void* d_out, int out_size, void* d_ws, size_t ws_size,
                              hipStream_t stream)
{
    const float* pred = (const float*)d_in[0];
    const float* targ = (const float*)d_in[1];
    const int n = in_sizes[0];
    const int rows = n / TLEN;   // 16

    const double csd = 1.0 - exp(-2200.0 / (50.0 * 44100.0));
    const double cld = 1.0 - exp(-2200.0 / (3000.0 * 44100.0));
    const double amSd = 1.0 - csd, amLd = 1.0 - cld;
    const float amS = (float)amSd, amL = (float)amLd;
    const float A16S   = (float)pow(amSd, 16.0);
    const float A1024S = (float)pow(amSd, 1024.0);
    const float A16L   = (float)pow(amLd, 16.0);
    const float A1024L = (float)pow(amLd, 1024.0);
    const float AcS  = (float)pow(amSd, 4096.0);
    const float AcS4 = (float)pow(amSd, 16384.0);
    const float AcL  = (float)pow(amLd, 4096.0);
    const float AcL4 = (float)pow(amLd, 16384.0);

    // ws layout: [0,8): double acc; then pB, cin (NEMA*rows*NCH floats each)
    char* wsb = (char*)d_ws;
    double* acc = (double*)wsb;
    float* pB  = (float*)(wsb + 256);
    float* cin = pB + (size_t)NEMA * rows * NCH;

    hipMemsetAsync(acc, 0, sizeof(double), stream);

    dim3 grid(NCH, rows);
    ldr_partials<<<grid, TPB, 0, stream>>>(pred, targ, amS, amL,
                                           A16S, A16L, pB, rows);
    ldr_carry<<<NEMA * rows, 64, 0, stream>>>(pB, cin, AcS, AcS4, AcL, AcL4, rows);
    ldr_loss<<<grid, TPB, 0, stream>>>(pred, targ, cin, amS, amL,
                                       A16S, A1024S, A16L, A1024L, acc, rows);

    const double inv_n = 1.0 / ((double)rows * (double)TLEN);
    ldr_finalize<<<1, 1, 0, stream>>>(acc, (float*)d_out, inv_n);
}